// Round 7
// baseline (965.917 us; speedup 1.0000x reference)
//
#include <hip/hip_runtime.h>
#include <hip/hip_bf16.h>

// TAGConv x2 GNN on MI355X. v7:
//  - v6 skeleton (G-slab [N][896] fp16 of dis*h_k, rs-recovery epilogue,
//    wave-per-node prop with 8 outstanding gathers).
//  - GEMM K-loop rewritten: RUNTIME loop, two K-tiles/iteration, statically
//    indexed double buffers -> bounded live ranges, no scratch spill
//    (v6's unrolled KITERS=14 spilled ~1.7KB/thread = 352MB writes/dispatch).

#define EPS_MSG 1e-7f
#define BNSCALE 0.9999950000374997f  // 1/sqrt(1+1e-5)
#define LO_INV 0.0009765625f         // 2^-10

typedef _Float16 half_t;
typedef _Float16 f16x8 __attribute__((ext_vector_type(8)));
typedef float f32x4 __attribute__((ext_vector_type(4)));

__device__ __forceinline__ float hlo(unsigned p) {
    unsigned short u = (unsigned short)(p & 0xffffu);
    half_t h;
    __builtin_memcpy(&h, &u, 2);
    return (float)h;
}
__device__ __forceinline__ float hhi(unsigned p) {
    unsigned short u = (unsigned short)(p >> 16);
    half_t h;
    __builtin_memcpy(&h, &u, 2);
    return (float)h;
}
__device__ __forceinline__ unsigned fpack2(float x, float y) {
    half_t a = (half_t)x, b = (half_t)y;
    unsigned short ua, ub;
    __builtin_memcpy(&ua, &a, 2);
    __builtin_memcpy(&ub, &b, 2);
    return (unsigned)ua | ((unsigned)ub << 16);
}

// ---------------- CSR build ----------------

__global__ void zero_i32(int* __restrict__ p, int n) {
    int i = blockIdx.x * blockDim.x + threadIdx.x;
    if (i < n) p[i] = 0;
}

__global__ void count_deg(const int* __restrict__ col, int* __restrict__ deg, int E) {
    int e = blockIdx.x * blockDim.x + threadIdx.x;
    if (e < E) atomicAdd(&deg[col[e]], 1);
}

__global__ void compute_dis_s(const int* __restrict__ deg, float* __restrict__ dis,
                              float* __restrict__ s, float* __restrict__ rs, int N) {
    int v = blockIdx.x * blockDim.x + threadIdx.x;
    if (v >= N) return;
    int d = deg[v];
    float di = (d > 0) ? rsqrtf((float)d) : 0.f;
    dis[v] = di;
    s[v] = (d > 0) ? di : 1.f;
    rs[v] = (d > 0) ? sqrtf((float)d) : 1.f;
}

__global__ void scan_blk(const int* __restrict__ deg, int* __restrict__ off,
                         int* __restrict__ bsum, int N) {
    __shared__ int sm[1024];
    int i = blockIdx.x * 1024 + threadIdx.x;
    sm[threadIdx.x] = (i < N) ? deg[i] : 0;
    __syncthreads();
    for (int ofs = 1; ofs < 1024; ofs <<= 1) {
        int t = (threadIdx.x >= (unsigned)ofs) ? sm[threadIdx.x - ofs] : 0;
        __syncthreads();
        sm[threadIdx.x] += t;
        __syncthreads();
    }
    if (i < N) off[i + 1] = sm[threadIdx.x];
    if (threadIdx.x == 0) bsum[blockIdx.x] = sm[1023];
}

__global__ void scan_top(int* __restrict__ bsum, int nb) {
    if (threadIdx.x == 0 && blockIdx.x == 0) {
        int a = 0;
        for (int b = 0; b < nb; ++b) {
            int t = bsum[b];
            bsum[b] = a;
            a += t;
        }
    }
}

__global__ void scan_add(int* __restrict__ off, const int* __restrict__ bsum, int N) {
    int i = blockIdx.x * 1024 + threadIdx.x;
    if (i < N) off[i + 1] += bsum[blockIdx.x];
    if (i == 0) off[0] = 0;
}

__global__ void fill_edges(const int* __restrict__ row, const int* __restrict__ col,
                           const int* __restrict__ off, int* __restrict__ cur,
                           unsigned short* __restrict__ esrc, int E) {
    int e = blockIdx.x * blockDim.x + threadIdx.x;
    if (e >= E) return;
    int c = col[e];
    int pos = off[c] + atomicAdd(&cur[c], 1);
    esrc[pos] = (unsigned short)row[e];
}

// ---------------- conversions ----------------

__global__ void conv_xg(const float* __restrict__ x, half_t* __restrict__ slab,
                        half_t* __restrict__ g0, const float* __restrict__ dis,
                        const float* __restrict__ s, int total) {
    int i = blockIdx.x * blockDim.x + threadIdx.x;
    if (i >= total) return;
    int v = i >> 7, c = i & 127;
    float xv = x[i];
    slab[(size_t)v * 896 + c] = (half_t)(s[v] * xv);
    g0[i] = (half_t)(dis[v] * fmaxf(xv, 0.f));
}

__device__ __forceinline__ void wcv(const float* __restrict__ in, half_t* __restrict__ oh,
                                    half_t* __restrict__ ol, int nm, int K, int Nn, int i) {
    int KT = nm * K;
    int n = i / KT;
    int rem = i - n * KT;
    int km = rem / K, k = rem - km * K;
    float w = in[(size_t)km * K * Nn + (size_t)k * Nn + n];
    half_t h = (half_t)w;
    oh[i] = h;
    ol[i] = (half_t)((w - (float)h) * 1024.f);
}

__global__ void conv_all(const float* l1, const float* l2, const float* a1, const float* b1,
                         const float* a2, const float* b2, half_t* W1h, half_t* W1l,
                         half_t* W2h, half_t* W2l, half_t* M1ah, half_t* M1al, half_t* M1bh,
                         half_t* M1bl, half_t* M2ah, half_t* M2al, half_t* M2bh,
                         half_t* M2bl) {
    int i = blockIdx.x * blockDim.x + threadIdx.x;
    if (i < 114688) {
        wcv(l1, W1h, W1l, 7, 128, 128, i);
    } else if (i < 172032) {
        wcv(l2, W2h, W2l, 7, 128, 64, i - 114688);
    } else if (i < 204800) {
        wcv(a1, M1ah, M1al, 1, 128, 256, i - 172032);
    } else if (i < 237568) {
        wcv(b1, M1bh, M1bl, 1, 256, 128, i - 204800);
    } else if (i < 245760) {
        wcv(a2, M2ah, M2al, 1, 64, 128, i - 237568);
    } else if (i < 253952) {
        wcv(b2, M2bh, M2bl, 1, 128, 64, i - 245760);
    }
}

// ---------------- propagation ----------------

__global__ void __launch_bounds__(256) prop(const unsigned* __restrict__ gin, int idl,
                                            unsigned* __restrict__ gout, int odl,
                                            const float* __restrict__ dis,
                                            const int* __restrict__ off,
                                            const unsigned short* __restrict__ esrc, int N) {
    const int lane = threadIdx.x & 63;
    const int w = threadIdx.x >> 6;
    const int stride = gridDim.x * 4;
    for (int v = blockIdx.x * 4 + w; v < N; v += stride) {
        int s = off[v], e = off[v + 1];
        float2 A0 = {0.f, 0.f}, A1 = {0.f, 0.f}, A2 = {0.f, 0.f}, A3 = {0.f, 0.f};
        float2 A4 = {0.f, 0.f}, A5 = {0.f, 0.f}, A6 = {0.f, 0.f}, A7 = {0.f, 0.f};
        for (int i = s; i < e; i += 8) {
            unsigned p[8];
            int ok[8];
#pragma unroll
            for (int j = 0; j < 8; ++j) {
                int ij = i + j;
                ok[j] = ij < e;
                int idx = ok[j] ? ij : e - 1;
                p[j] = gin[esrc[idx] * idl + lane];
            }
            A0.x += ok[0] ? hlo(p[0]) : 0.f; A0.y += ok[0] ? hhi(p[0]) : 0.f;
            A1.x += ok[1] ? hlo(p[1]) : 0.f; A1.y += ok[1] ? hhi(p[1]) : 0.f;
            A2.x += ok[2] ? hlo(p[2]) : 0.f; A2.y += ok[2] ? hhi(p[2]) : 0.f;
            A3.x += ok[3] ? hlo(p[3]) : 0.f; A3.y += ok[3] ? hhi(p[3]) : 0.f;
            A4.x += ok[4] ? hlo(p[4]) : 0.f; A4.y += ok[4] ? hhi(p[4]) : 0.f;
            A5.x += ok[5] ? hlo(p[5]) : 0.f; A5.y += ok[5] ? hhi(p[5]) : 0.f;
            A6.x += ok[6] ? hlo(p[6]) : 0.f; A6.y += ok[6] ? hhi(p[6]) : 0.f;
            A7.x += ok[7] ? hlo(p[7]) : 0.f; A7.y += ok[7] ? hhi(p[7]) : 0.f;
        }
        float ax = ((A0.x + A1.x) + (A2.x + A3.x)) + ((A4.x + A5.x) + (A6.x + A7.x));
        float ay = ((A0.y + A1.y) + (A2.y + A3.y)) + ((A4.y + A5.y) + (A6.y + A7.y));
        float dv = dis[v];
        float ce = (float)(e - s) * EPS_MSG;
        float hx = fmaf(dv, ax, ce);
        float hy = fmaf(dv, ay, ce);
        gout[v * odl + lane] = fpack2(dv * hx, dv * hy);
    }
}

// ---------------- f16 MFMA GEMM (runtime K-loop, 2 tiles/iter) ----------------
// C[M,*](ldc) = epi( rs .* (A[M,K] @ (Bh + Bl/1024)^T) )
// epi: 1=+bias 2=relu(bn(v+bias)) 3=relu(v+bias)

template <int BN, int OUTF32>
__global__ __launch_bounds__(256) void gemm(
    int M, int kiters, const half_t* __restrict__ A, int lda,
    const half_t* __restrict__ Bhp, const half_t* __restrict__ Blp, int ldb,
    void* __restrict__ Cp, int ldc, const float* __restrict__ rs, int epi,
    const float* __restrict__ bias, const float* __restrict__ bng,
    const float* __restrict__ bnb, half_t* __restrict__ goutP, int ldp,
    const float* __restrict__ sArr, half_t* __restrict__ goutG, int ldg,
    const float* __restrict__ disArr) {
    constexpr int BM = 64, BK = 64, PADE = 72;  // 144B rows: odd multiple of 16B
    constexpr int WC = (BN == 128) ? 2 : 1;
    constexpr int WROWS = BM / (4 / WC);  // 32 or 16
    constexpr int MF = WROWS / 16;
    constexpr int NF = 4;
    constexpr int AIT = 2;
    constexpr int BIT = (BN * BK) / (256 * 8);  // 4 or 2

    __shared__ half_t Ahs[BM][PADE];
    __shared__ half_t Bhs[BN][PADE];
    __shared__ half_t Bls[BN][PADE];

    const int tid = threadIdx.x;
    const int lane = tid & 63;
    const int w = tid >> 6;
    const int wr = w / WC, wc = w % WC;
    const int m0 = blockIdx.x * BM;
    const int n0 = blockIdx.y * BN;

    uint4 ra0[AIT], ra1[AIT];
    uint4 rb0h[BIT], rb0l[BIT], rb1h[BIT], rb1l[BIT];

    auto loadA = [&](uint4(&dst)[AIT], int k0) {
#pragma unroll
        for (int it = 0; it < AIT; ++it) {
            int f = (tid + it * 256) * 8;
            int r = f >> 6, kk = f & 63;
            int gv = m0 + r;
            dst[it] = (gv < M)
                          ? *reinterpret_cast<const uint4*>(&A[(size_t)gv * lda + k0 + kk])
                          : make_uint4(0u, 0u, 0u, 0u);
        }
    };
    auto loadB = [&](uint4(&dh)[BIT], uint4(&dl)[BIT], int k0) {
#pragma unroll
        for (int it = 0; it < BIT; ++it) {
            int f = (tid + it * 256) * 8;
            int r = f >> 6, kk = f & 63;
            dh[it] = *reinterpret_cast<const uint4*>(&Bhp[(size_t)(n0 + r) * ldb + k0 + kk]);
            dl[it] = *reinterpret_cast<const uint4*>(&Blp[(size_t)(n0 + r) * ldb + k0 + kk]);
        }
    };
    auto writeT = [&](uint4(&a)[AIT], uint4(&bh)[BIT], uint4(&bl)[BIT]) {
#pragma unroll
        for (int it = 0; it < AIT; ++it) {
            int f = (tid + it * 256) * 8;
            int r = f >> 6, kk = f & 63;
            *reinterpret_cast<uint4*>(&Ahs[r][kk]) = a[it];
        }
#pragma unroll
        for (int it = 0; it < BIT; ++it) {
            int f = (tid + it * 256) * 8;
            int r = f >> 6, kk = f & 63;
            *reinterpret_cast<uint4*>(&Bhs[r][kk]) = bh[it];
            *reinterpret_cast<uint4*>(&Bls[r][kk]) = bl[it];
        }
    };

    f32x4 acch[MF][NF], accl[MF][NF];
#pragma unroll
    for (int fm = 0; fm < MF; ++fm)
#pragma unroll
        for (int fn = 0; fn < NF; ++fn) {
            acch[fm][fn] = (f32x4){0.f, 0.f, 0.f, 0.f};
            accl[fm][fn] = (f32x4){0.f, 0.f, 0.f, 0.f};
        }

    auto compute = [&]() {
#pragma unroll
        for (int ks = 0; ks < 2; ++ks) {
            const int ko = ks * 32 + (lane >> 4) * 8;
            f16x8 af[MF];
#pragma unroll
            for (int fm = 0; fm < MF; ++fm)
                af[fm] =
                    *reinterpret_cast<const f16x8*>(&Ahs[wr * WROWS + fm * 16 + (lane & 15)][ko]);
#pragma unroll
            for (int fn = 0; fn < NF; ++fn) {
                const int colb = wc * 64 + fn * 16 + (lane & 15);
                f16x8 bhv = *reinterpret_cast<const f16x8*>(&Bhs[colb][ko]);
                f16x8 blv = *reinterpret_cast<const f16x8*>(&Bls[colb][ko]);
#pragma unroll
                for (int fm = 0; fm < MF; ++fm) {
                    acch[fm][fn] =
                        __builtin_amdgcn_mfma_f32_16x16x32_f16(af[fm], bhv, acch[fm][fn], 0, 0, 0);
                    accl[fm][fn] =
                        __builtin_amdgcn_mfma_f32_16x16x32_f16(af[fm], blv, accl[fm][fn], 0, 0, 0);
                }
            }
        }
    };

    // prologue: tile 0 -> buf0
    loadB(rb0h, rb0l, 0);
    loadA(ra0, 0);

    int kt = 0;
    for (; kt + 2 <= kiters; kt += 2) {
        // tile kt (buf0)
        writeT(ra0, rb0h, rb0l);
        __syncthreads();
        if (kt + 1 < kiters) {
            loadB(rb1h, rb1l, (kt + 1) * BK);
            loadA(ra1, (kt + 1) * BK);
        }
        compute();
        __syncthreads();
        // tile kt+1 (buf1)
        writeT(ra1, rb1h, rb1l);
        __syncthreads();
        if (kt + 2 < kiters) {
            loadB(rb0h, rb0l, (kt + 2) * BK);
            loadA(ra0, (kt + 2) * BK);
        }
        compute();
        __syncthreads();
    }
    if (kt < kiters) {  // odd tail: tile kt sits in buf0
        writeT(ra0, rb0h, rb0l);
        __syncthreads();
        compute();
    }

    // C/D layout: col = lane&15, row = (lane>>4)*4 + i
#pragma unroll
    for (int fm = 0; fm < MF; ++fm)
#pragma unroll
        for (int fn = 0; fn < NF; ++fn)
#pragma unroll
            for (int i = 0; i < 4; ++i) {
                int gr = m0 + wr * WROWS + fm * 16 + (lane >> 4) * 4 + i;
                if (gr >= M) continue;
                int gc = n0 + wc * 64 + fn * 16 + (lane & 15);
                float v = acch[fm][fn][i] + accl[fm][fn][i] * LO_INV;
                if (rs) v *= rs[gr];
                if (epi == 1) {
                    v += bias[gc];
                } else if (epi == 2) {
                    v = bng[gc] * ((v + bias[gc]) * BNSCALE) + bnb[gc];
                    v = fmaxf(v, 0.f);
                } else if (epi == 3) {
                    v = fmaxf(v + bias[gc], 0.f);
                }
                if (Cp) {
                    if (OUTF32)
                        ((float*)Cp)[(size_t)gr * ldc + gc] = v;
                    else
                        ((half_t*)Cp)[(size_t)gr * ldc + gc] = (half_t)v;
                }
                if (goutP) goutP[(size_t)gr * ldp + gc] = (half_t)(sArr[gr] * v);
                if (goutG) goutG[(size_t)gr * ldg + gc] = (half_t)(disArr[gr] * v);
            }
}

extern "C" void kernel_launch(void* const* d_in, const int* in_sizes, int n_in,
                              void* d_out, int out_size, void* d_ws, size_t ws_size,
                              hipStream_t stream) {
    const float* x     = (const float*)d_in[0];
    const int*   ei    = (const int*)d_in[1];
    const float* lins1 = (const float*)d_in[2];
    const float* bias1 = (const float*)d_in[3];
    const float* m1w1  = (const float*)d_in[4];
    const float* m1b1  = (const float*)d_in[5];
    const float* bn1g  = (const float*)d_in[6];
    const float* bn1b  = (const float*)d_in[7];
    const float* m1w2  = (const float*)d_in[8];
    const float* m1b2  = (const float*)d_in[9];
    const float* lins2 = (const float*)d_in[10];
    const float* bias2 = (const float*)d_in[11];
    const float* m2w1  = (const float*)d_in[12];
    const float* m2b1  = (const float*)d_in[13];
    const float* bn2g  = (const float*)d_in[14];
    const float* bn2b  = (const float*)d_in[15];
    const float* m2w2  = (const float*)d_in[16];
    const float* m2b2  = (const float*)d_in[17];
    float* out = (float*)d_out;

    const int N = in_sizes[0] / 128;
    const int E = in_sizes[1] / 2;
    const int* row = ei;
    const int* col = ei + E;

    char* ws = (char*)d_ws;
    size_t o = 0;
    auto alloc = [&](size_t bytes) {
        void* p = ws + o;
        o += (bytes + 255) & ~(size_t)255;
        return p;
    };
    int*            deg  = (int*)alloc((size_t)N * 4);
    int*            cur  = (int*)alloc((size_t)N * 4);
    float*          dis  = (float*)alloc((size_t)N * 4);
    float*          sA   = (float*)alloc((size_t)N * 4);
    float*          rsA  = (float*)alloc((size_t)N * 4);
    int*            off  = (int*)alloc((size_t)(N + 1) * 4);
    int*            bsum = (int*)alloc(1024 * 4);
    unsigned short* esrc = (unsigned short*)alloc((size_t)E * 2);
    half_t* g0    = (half_t*)alloc((size_t)N * 128 * 2);
    half_t* ACC   = (half_t*)alloc((size_t)N * 128 * 2);
    half_t* Z     = (half_t*)alloc((size_t)N * 256 * 2);
    half_t* ACC2  = (half_t*)alloc((size_t)N * 64 * 2);
    half_t* Wc1h  = (half_t*)alloc((size_t)128 * 896 * 2);
    half_t* Wc1l  = (half_t*)alloc((size_t)128 * 896 * 2);
    half_t* Wc2h  = (half_t*)alloc((size_t)64 * 896 * 2);
    half_t* Wc2l  = (half_t*)alloc((size_t)64 * 896 * 2);
    half_t* Wm1ah = (half_t*)alloc((size_t)256 * 128 * 2);
    half_t* Wm1al = (half_t*)alloc((size_t)256 * 128 * 2);
    half_t* Wm1bh = (half_t*)alloc((size_t)128 * 256 * 2);
    half_t* Wm1bl = (half_t*)alloc((size_t)128 * 256 * 2);
    half_t* Wm2ah = (half_t*)alloc((size_t)128 * 64 * 2);
    half_t* Wm2al = (half_t*)alloc((size_t)128 * 64 * 2);
    half_t* Wm2bh = (half_t*)alloc((size_t)64 * 128 * 2);
    half_t* Wm2bl = (half_t*)alloc((size_t)64 * 128 * 2);
    half_t* slab  = (half_t*)alloc((size_t)N * 896 * 2);
    (void)ws_size;

    const int TPB = 256;
    const int nb = (N + 1023) / 1024;
    zero_i32<<<(N + TPB - 1) / TPB, TPB, 0, stream>>>(deg, N);
    zero_i32<<<(N + TPB - 1) / TPB, TPB, 0, stream>>>(cur, N);
    count_deg<<<(E + TPB - 1) / TPB, TPB, 0, stream>>>(col, deg, E);
    compute_dis_s<<<(N + TPB - 1) / TPB, TPB, 0, stream>>>(deg, dis, sA, rsA, N);
    scan_blk<<<nb, 1024, 0, stream>>>(deg, off, bsum, N);
    scan_top<<<1, 64, 0, stream>>>(bsum, nb);
    scan_add<<<nb, 1024, 0, stream>>>(off, bsum, N);
    fill_edges<<<(E + TPB - 1) / TPB, TPB, 0, stream>>>(row, col, off, cur, esrc, E);
    conv_all<<<(253952 + TPB - 1) / TPB, TPB, 0, stream>>>(
        lins1, lins2, m1w1, m1w2, m2w1, m2w2, Wc1h, Wc1l, Wc2h, Wc2l, Wm1ah, Wm1al, Wm1bh,
        Wm1bl, Wm2ah, Wm2al, Wm2bh, Wm2bl);
    conv_xg<<<(N * 128 + TPB - 1) / TPB, TPB, 0, stream>>>(x, slab, g0, dis, sA, N * 128);

    unsigned* slabU = (unsigned*)slab;
    unsigned* g0U = (unsigned*)g0;
    const int HG = (N + 63) / 64;
    auto launch_prop = [&](const unsigned* gi, int idl, unsigned* go, int odl) {
        prop<<<2048, 256, 0, stream>>>(gi, idl, go, odl, dis, off, esrc, N);
    };

    // ---- Layer 1: 6 hops into slab cols 1..6 ----
    launch_prop(g0U, 64, slabU + 64, 448);
    for (int k = 2; k <= 6; ++k)
        launch_prop(slabU + (size_t)(k - 1) * 64, 448, slabU + (size_t)k * 64, 448);
    // concat GEMM K=896 -> ACC
    gemm<128, 0><<<dim3(HG, 1), 256, 0, stream>>>(
        N, 14, slab, 896, Wc1h, Wc1l, 896, ACC, 128, rsA, 1, bias1, nullptr, nullptr, nullptr, 0,
        nullptr, nullptr, 0, nullptr);
    // MLP1a: Z = relu(bn(ACC@W+b))  [N,256]
    gemm<128, 0><<<dim3(HG, 2), 256, 0, stream>>>(
        N, 2, ACC, 128, Wm1ah, Wm1al, 128, Z, 256, nullptr, 2, m1b1, bn1g, bn1b, nullptr, 0,
        nullptr, nullptr, 0, nullptr);
    // MLP1b: h1 = relu(Z@W+b); slab col0 = s*h1, g0 = dis*h1
    gemm<128, 0><<<dim3(HG, 1), 256, 0, stream>>>(
        N, 4, Z, 256, Wm1bh, Wm1bl, 256, nullptr, 0, nullptr, 3, m1b2, nullptr, nullptr, slab,
        896, sA, g0, 128, dis);

    // ---- Layer 2: 6 hops ----
    launch_prop(g0U, 64, slabU + 64, 448);
    for (int k = 2; k <= 6; ++k)
        launch_prop(slabU + (size_t)(k - 1) * 64, 448, slabU + (size_t)k * 64, 448);
    // concat GEMM K=896, Ntot=64 -> ACC2
    gemm<64, 0><<<dim3(HG, 1), 256, 0, stream>>>(
        N, 14, slab, 896, Wc2h, Wc2l, 896, ACC2, 64, rsA, 1, bias2, nullptr, nullptr, nullptr, 0,
        nullptr, nullptr, 0, nullptr);
    // MLP2a: Z2 = relu(bn(ACC2@W+b)) [N,128] (reuse Z)
    gemm<128, 0><<<dim3(HG, 1), 256, 0, stream>>>(
        N, 1, ACC2, 64, Wm2ah, Wm2al, 64, Z, 128, nullptr, 2, m2b1, bn2g, bn2b, nullptr, 0,
        nullptr, nullptr, 0, nullptr);
    // MLP2b: out = Z2@W + b (fp32)
    gemm<64, 1><<<dim3(HG, 1), 256, 0, stream>>>(
        N, 2, Z, 128, Wm2bh, Wm2bl, 128, out, 64, nullptr, 1, m2b2, nullptr, nullptr, nullptr, 0,
        nullptr, nullptr, 0, nullptr);
}

// Round 8
// 752.607 us; speedup vs baseline: 1.2834x; 1.2834x over previous
//
#include <hip/hip_runtime.h>
#include <hip/hip_bf16.h>

// TAGConv x2 GNN on MI355X. v8:
//  - GEMM staging via __builtin_amdgcn_global_load_lds (16B/lane, no staging
//    VGPRs -> kills the 340MB/dispatch scratch spill of v6/v7).
//  - linear LDS dest + XOR-swizzled global source + swizzled ds_read
//    (chunk ^= row&7) -> no bank conflict, no padding.
//  - double-buffered LDS, ONE barrier per K-tile, runtime K-loop.
//  - rest identical to v7 (G-slab [N][896] of dis*h_k, rs-recovery epilogue,
//    wave-per-node prop with 8 outstanding gathers, split-B hi/lo f16 MFMA).

#define EPS_MSG 1e-7f
#define BNSCALE 0.9999950000374997f  // 1/sqrt(1+1e-5)
#define LO_INV 0.0009765625f         // 2^-10

typedef _Float16 half_t;
typedef _Float16 f16x8 __attribute__((ext_vector_type(8)));
typedef float f32x4 __attribute__((ext_vector_type(4)));

__device__ __forceinline__ void gld16(const char* g, char* l) {
    __builtin_amdgcn_global_load_lds(
        (const __attribute__((address_space(1))) void*)g,
        (__attribute__((address_space(3))) void*)l, 16, 0, 0);
}

__device__ __forceinline__ float hlo(unsigned p) {
    unsigned short u = (unsigned short)(p & 0xffffu);
    half_t h;
    __builtin_memcpy(&h, &u, 2);
    return (float)h;
}
__device__ __forceinline__ float hhi(unsigned p) {
    unsigned short u = (unsigned short)(p >> 16);
    half_t h;
    __builtin_memcpy(&h, &u, 2);
    return (float)h;
}
__device__ __forceinline__ unsigned fpack2(float x, float y) {
    half_t a = (half_t)x, b = (half_t)y;
    unsigned short ua, ub;
    __builtin_memcpy(&ua, &a, 2);
    __builtin_memcpy(&ub, &b, 2);
    return (unsigned)ua | ((unsigned)ub << 16);
}

// ---------------- CSR build ----------------

__global__ void zero_i32(int* __restrict__ p, int n) {
    int i = blockIdx.x * blockDim.x + threadIdx.x;
    if (i < n) p[i] = 0;
}

__global__ void count_deg(const int* __restrict__ col, int* __restrict__ deg, int E) {
    int e = blockIdx.x * blockDim.x + threadIdx.x;
    if (e < E) atomicAdd(&deg[col[e]], 1);
}

__global__ void compute_dis_s(const int* __restrict__ deg, float* __restrict__ dis,
                              float* __restrict__ s, float* __restrict__ rs, int N) {
    int v = blockIdx.x * blockDim.x + threadIdx.x;
    if (v >= N) return;
    int d = deg[v];
    float di = (d > 0) ? rsqrtf((float)d) : 0.f;
    dis[v] = di;
    s[v] = (d > 0) ? di : 1.f;
    rs[v] = (d > 0) ? sqrtf((float)d) : 1.f;
}

__global__ void scan_blk(const int* __restrict__ deg, int* __restrict__ off,
                         int* __restrict__ bsum, int N) {
    __shared__ int sm[1024];
    int i = blockIdx.x * 1024 + threadIdx.x;
    sm[threadIdx.x] = (i < N) ? deg[i] : 0;
    __syncthreads();
    for (int ofs = 1; ofs < 1024; ofs <<= 1) {
        int t = (threadIdx.x >= (unsigned)ofs) ? sm[threadIdx.x - ofs] : 0;
        __syncthreads();
        sm[threadIdx.x] += t;
        __syncthreads();
    }
    if (i < N) off[i + 1] = sm[threadIdx.x];
    if (threadIdx.x == 0) bsum[blockIdx.x] = sm[1023];
}

__global__ void scan_top(int* __restrict__ bsum, int nb) {
    if (threadIdx.x == 0 && blockIdx.x == 0) {
        int a = 0;
        for (int b = 0; b < nb; ++b) {
            int t = bsum[b];
            bsum[b] = a;
            a += t;
        }
    }
}

__global__ void scan_add(int* __restrict__ off, const int* __restrict__ bsum, int N) {
    int i = blockIdx.x * 1024 + threadIdx.x;
    if (i < N) off[i + 1] += bsum[blockIdx.x];
    if (i == 0) off[0] = 0;
}

__global__ void fill_edges(const int* __restrict__ row, const int* __restrict__ col,
                           const int* __restrict__ off, int* __restrict__ cur,
                           unsigned short* __restrict__ esrc, int E) {
    int e = blockIdx.x * blockDim.x + threadIdx.x;
    if (e >= E) return;
    int c = col[e];
    int pos = off[c] + atomicAdd(&cur[c], 1);
    esrc[pos] = (unsigned short)row[e];
}

// ---------------- conversions ----------------

__global__ void conv_xg(const float* __restrict__ x, half_t* __restrict__ slab,
                        half_t* __restrict__ g0, const float* __restrict__ dis,
                        const float* __restrict__ s, int total) {
    int i = blockIdx.x * blockDim.x + threadIdx.x;
    if (i >= total) return;
    int v = i >> 7, c = i & 127;
    float xv = x[i];
    slab[(size_t)v * 896 + c] = (half_t)(s[v] * xv);
    g0[i] = (half_t)(dis[v] * fmaxf(xv, 0.f));
}

__device__ __forceinline__ void wcv(const float* __restrict__ in, half_t* __restrict__ oh,
                                    half_t* __restrict__ ol, int nm, int K, int Nn, int i) {
    int KT = nm * K;
    int n = i / KT;
    int rem = i - n * KT;
    int km = rem / K, k = rem - km * K;
    float w = in[(size_t)km * K * Nn + (size_t)k * Nn + n];
    half_t h = (half_t)w;
    oh[i] = h;
    ol[i] = (half_t)((w - (float)h) * 1024.f);
}

__global__ void conv_all(const float* l1, const float* l2, const float* a1, const float* b1,
                         const float* a2, const float* b2, half_t* W1h, half_t* W1l,
                         half_t* W2h, half_t* W2l, half_t* M1ah, half_t* M1al, half_t* M1bh,
                         half_t* M1bl, half_t* M2ah, half_t* M2al, half_t* M2bh,
                         half_t* M2bl) {
    int i = blockIdx.x * blockDim.x + threadIdx.x;
    if (i < 114688) {
        wcv(l1, W1h, W1l, 7, 128, 128, i);
    } else if (i < 172032) {
        wcv(l2, W2h, W2l, 7, 128, 64, i - 114688);
    } else if (i < 204800) {
        wcv(a1, M1ah, M1al, 1, 128, 256, i - 172032);
    } else if (i < 237568) {
        wcv(b1, M1bh, M1bl, 1, 256, 128, i - 204800);
    } else if (i < 245760) {
        wcv(a2, M2ah, M2al, 1, 64, 128, i - 237568);
    } else if (i < 253952) {
        wcv(b2, M2bh, M2bl, 1, 128, 64, i - 245760);
    }
}

// ---------------- propagation ----------------

__global__ void __launch_bounds__(256) prop(const unsigned* __restrict__ gin, int idl,
                                            unsigned* __restrict__ gout, int odl,
                                            const float* __restrict__ dis,
                                            const int* __restrict__ off,
                                            const unsigned short* __restrict__ esrc, int N) {
    const int lane = threadIdx.x & 63;
    const int w = threadIdx.x >> 6;
    const int stride = gridDim.x * 4;
    for (int v = blockIdx.x * 4 + w; v < N; v += stride) {
        int s = off[v], e = off[v + 1];
        float2 A0 = {0.f, 0.f}, A1 = {0.f, 0.f}, A2 = {0.f, 0.f}, A3 = {0.f, 0.f};
        float2 A4 = {0.f, 0.f}, A5 = {0.f, 0.f}, A6 = {0.f, 0.f}, A7 = {0.f, 0.f};
        for (int i = s; i < e; i += 8) {
            unsigned p[8];
            int ok[8];
#pragma unroll
            for (int j = 0; j < 8; ++j) {
                int ij = i + j;
                ok[j] = ij < e;
                int idx = ok[j] ? ij : e - 1;
                p[j] = gin[esrc[idx] * idl + lane];
            }
            A0.x += ok[0] ? hlo(p[0]) : 0.f; A0.y += ok[0] ? hhi(p[0]) : 0.f;
            A1.x += ok[1] ? hlo(p[1]) : 0.f; A1.y += ok[1] ? hhi(p[1]) : 0.f;
            A2.x += ok[2] ? hlo(p[2]) : 0.f; A2.y += ok[2] ? hhi(p[2]) : 0.f;
            A3.x += ok[3] ? hlo(p[3]) : 0.f; A3.y += ok[3] ? hhi(p[3]) : 0.f;
            A4.x += ok[4] ? hlo(p[4]) : 0.f; A4.y += ok[4] ? hhi(p[4]) : 0.f;
            A5.x += ok[5] ? hlo(p[5]) : 0.f; A5.y += ok[5] ? hhi(p[5]) : 0.f;
            A6.x += ok[6] ? hlo(p[6]) : 0.f; A6.y += ok[6] ? hhi(p[6]) : 0.f;
            A7.x += ok[7] ? hlo(p[7]) : 0.f; A7.y += ok[7] ? hhi(p[7]) : 0.f;
        }
        float ax = ((A0.x + A1.x) + (A2.x + A3.x)) + ((A4.x + A5.x) + (A6.x + A7.x));
        float ay = ((A0.y + A1.y) + (A2.y + A3.y)) + ((A4.y + A5.y) + (A6.y + A7.y));
        float dv = dis[v];
        float ce = (float)(e - s) * EPS_MSG;
        float hx = fmaf(dv, ax, ce);
        float hy = fmaf(dv, ay, ce);
        gout[v * odl + lane] = fpack2(dv * hx, dv * hy);
    }
}

// ---------------- f16 MFMA GEMM (global_load_lds, swizzled, dbuf LDS) -------
// C[M,*](ldc) = epi( rs .* (A[M,K] @ (Bh + Bl/1024)^T) )
// epi: 1=+bias 2=relu(bn(v+bias)) 3=relu(v+bias)

template <int BN, int OUTF32>
__global__ __launch_bounds__(256) void gemm(
    int M, int kiters, const half_t* __restrict__ A, int lda,
    const half_t* __restrict__ Bhp, const half_t* __restrict__ Blp, int ldb,
    void* __restrict__ Cp, int ldc, const float* __restrict__ rs, int epi,
    const float* __restrict__ bias, const float* __restrict__ bng,
    const float* __restrict__ bnb, half_t* __restrict__ goutP, int ldp,
    const float* __restrict__ sArr, half_t* __restrict__ goutG, int ldg,
    const float* __restrict__ disArr) {
    constexpr int BM = 64, BK = 64;
    constexpr int WC = (BN == 128) ? 2 : 1;
    constexpr int WROWS = BM / (4 / WC);  // 32 or 16
    constexpr int MF = WROWS / 16;
    constexpr int NF = 4;
    constexpr int ABY = BM * BK * 2;      // 8192 B
    constexpr int BBY = BN * BK * 2;      // 16384 / 8192 B
    constexpr int BUFBY = ABY + 2 * BBY;  // 40960 / 24576 B
    constexpr int ACW = (ABY / 1024) / 4; // A chunks per wave: 2
    constexpr int BCW = (BBY / 1024) / 4; // B chunks per wave per plane: 4 / 2

    __shared__ char lds[2][BUFBY];

    const int tid = threadIdx.x;
    const int lane = tid & 63;
    const int w = tid >> 6;
    const int wr = w / WC, wc = w % WC;
    const int m0 = blockIdx.x * BM;
    const int n0 = blockIdx.y * BN;
    const int l15 = lane & 15, lq = lane >> 4;
    const int lr8 = lane >> 3, lc8 = lane & 7;  // chunk-local row / 16B-col

    const char* gA = (const char*)A;
    const char* gBh = (const char*)Bhp;
    const char* gBl = (const char*)Blp;
    const size_t ldaB = (size_t)lda * 2, ldbB = (size_t)ldb * 2;

    auto stage = [&](int kt, int buf) {
        const int k0b = kt * BK * 2;
        char* base = lds[0] + buf * BUFBY;
#pragma unroll
        for (int i = 0; i < ACW; ++i) {
            int c = w * ACW + i;
            int r = c * 8 + lr8;
            int gv = m0 + r;
            if (gv >= M) gv = M - 1;
            int sc = (lc8 ^ (r & 7)) << 4;  // swizzled 16B col
            gld16(gA + (size_t)gv * ldaB + k0b + sc, base + c * 1024);
        }
#pragma unroll
        for (int i = 0; i < BCW; ++i) {
            int c = w * BCW + i;
            int r = c * 8 + lr8;
            int sc = (lc8 ^ (r & 7)) << 4;
            size_t goff = (size_t)(n0 + r) * ldbB + k0b + sc;
            gld16(gBh + goff, base + ABY + c * 1024);
            gld16(gBl + goff, base + ABY + BBY + c * 1024);
        }
    };

    f32x4 acch[MF][NF], accl[MF][NF];
#pragma unroll
    for (int fm = 0; fm < MF; ++fm)
#pragma unroll
        for (int fn = 0; fn < NF; ++fn) {
            acch[fm][fn] = (f32x4){0.f, 0.f, 0.f, 0.f};
            accl[fm][fn] = (f32x4){0.f, 0.f, 0.f, 0.f};
        }

    auto compute = [&](int buf) {
        const char* Ab = lds[0] + buf * BUFBY;
        const char* Bhb = Ab + ABY;
        const char* Blb = Ab + ABY + BBY;
#pragma unroll
        for (int ks = 0; ks < 2; ++ks) {
            const int cc = ks * 4 + lq;  // 16B-chunk index within the 128B row
            f16x8 af[MF];
#pragma unroll
            for (int fm = 0; fm < MF; ++fm) {
                int r = wr * WROWS + fm * 16 + l15;
                af[fm] = *(const f16x8*)(Ab + r * 128 + ((cc ^ (r & 7)) << 4));
            }
#pragma unroll
            for (int fn = 0; fn < NF; ++fn) {
                int r = wc * 64 + fn * 16 + l15;
                int o = r * 128 + ((cc ^ (r & 7)) << 4);
                f16x8 bhv = *(const f16x8*)(Bhb + o);
                f16x8 blv = *(const f16x8*)(Blb + o);
#pragma unroll
                for (int fm = 0; fm < MF; ++fm) {
                    acch[fm][fn] =
                        __builtin_amdgcn_mfma_f32_16x16x32_f16(af[fm], bhv, acch[fm][fn], 0, 0, 0);
                    accl[fm][fn] =
                        __builtin_amdgcn_mfma_f32_16x16x32_f16(af[fm], blv, accl[fm][fn], 0, 0, 0);
                }
            }
        }
    };

    stage(0, 0);
    int buf = 0;
    for (int kt = 0; kt < kiters; ++kt) {
        __syncthreads();  // drains vmcnt: stage(kt) complete; prev compute done
        if (kt + 1 < kiters) stage(kt + 1, buf ^ 1);
        compute(buf);
        buf ^= 1;
    }

    // C/D layout: col = lane&15, row = (lane>>4)*4 + i
#pragma unroll
    for (int fm = 0; fm < MF; ++fm)
#pragma unroll
        for (int fn = 0; fn < NF; ++fn)
#pragma unroll
            for (int i = 0; i < 4; ++i) {
                int gr = m0 + wr * WROWS + fm * 16 + (lane >> 4) * 4 + i;
                if (gr >= M) continue;
                int gc = n0 + wc * 64 + fn * 16 + (lane & 15);
                float v = acch[fm][fn][i] + accl[fm][fn][i] * LO_INV;
                if (rs) v *= rs[gr];
                if (epi == 1) {
                    v += bias[gc];
                } else if (epi == 2) {
                    v = bng[gc] * ((v + bias[gc]) * BNSCALE) + bnb[gc];
                    v = fmaxf(v, 0.f);
                } else if (epi == 3) {
                    v = fmaxf(v + bias[gc], 0.f);
                }
                if (Cp) {
                    if (OUTF32)
                        ((float*)Cp)[(size_t)gr * ldc + gc] = v;
                    else
                        ((half_t*)Cp)[(size_t)gr * ldc + gc] = (half_t)v;
                }
                if (goutP) goutP[(size_t)gr * ldp + gc] = (half_t)(sArr[gr] * v);
                if (goutG) goutG[(size_t)gr * ldg + gc] = (half_t)(disArr[gr] * v);
            }
}

extern "C" void kernel_launch(void* const* d_in, const int* in_sizes, int n_in,
                              void* d_out, int out_size, void* d_ws, size_t ws_size,
                              hipStream_t stream) {
    const float* x     = (const float*)d_in[0];
    const int*   ei    = (const int*)d_in[1];
    const float* lins1 = (const float*)d_in[2];
    const float* bias1 = (const float*)d_in[3];
    const float* m1w1  = (const float*)d_in[4];
    const float* m1b1  = (const float*)d_in[5];
    const float* bn1g  = (const float*)d_in[6];
    const float* bn1b  = (const float*)d_in[7];
    const float* m1w2  = (const float*)d_in[8];
    const float* m1b2  = (const float*)d_in[9];
    const float* lins2 = (const float*)d_in[10];
    const float* bias2 = (const float*)d_in[11];
    const float* m2w1  = (const float*)d_in[12];
    const float* m2b1  = (const float*)d_in[13];
    const float* bn2g  = (const float*)d_in[14];
    const float* bn2b  = (const float*)d_in[15];
    const float* m2w2  = (const float*)d_in[16];
    const float* m2b2  = (const float*)d_in[17];
    float* out = (float*)d_out;

    const int N = in_sizes[0] / 128;
    const int E = in_sizes[1] / 2;
    const int* row = ei;
    const int* col = ei + E;

    char* ws = (char*)d_ws;
    size_t o = 0;
    auto alloc = [&](size_t bytes) {
        void* p = ws + o;
        o += (bytes + 255) & ~(size_t)255;
        return p;
    };
    int*            deg  = (int*)alloc((size_t)N * 4);
    int*            cur  = (int*)alloc((size_t)N * 4);
    float*          dis  = (float*)alloc((size_t)N * 4);
    float*          sA   = (float*)alloc((size_t)N * 4);
    float*          rsA  = (float*)alloc((size_t)N * 4);
    int*            off  = (int*)alloc((size_t)(N + 1) * 4);
    int*            bsum = (int*)alloc(1024 * 4);
    unsigned short* esrc = (unsigned short*)alloc((size_t)E * 2);
    half_t* g0    = (half_t*)alloc((size_t)N * 128 * 2);
    half_t* ACC   = (half_t*)alloc((size_t)N * 128 * 2);
    half_t* Z     = (half_t*)alloc((size_t)N * 256 * 2);
    half_t* ACC2  = (half_t*)alloc((size_t)N * 64 * 2);
    half_t* Wc1h  = (half_t*)alloc((size_t)128 * 896 * 2);
    half_t* Wc1l  = (half_t*)alloc((size_t)128 * 896 * 2);
    half_t* Wc2h  = (half_t*)alloc((size_t)64 * 896 * 2);
    half_t* Wc2l  = (half_t*)alloc((size_t)64 * 896 * 2);
    half_t* Wm1ah = (half_t*)alloc((size_t)256 * 128 * 2);
    half_t* Wm1al = (half_t*)alloc((size_t)256 * 128 * 2);
    half_t* Wm1bh = (half_t*)alloc((size_t)128 * 256 * 2);
    half_t* Wm1bl = (half_t*)alloc((size_t)128 * 256 * 2);
    half_t* Wm2ah = (half_t*)alloc((size_t)128 * 64 * 2);
    half_t* Wm2al = (half_t*)alloc((size_t)128 * 64 * 2);
    half_t* Wm2bh = (half_t*)alloc((size_t)64 * 128 * 2);
    half_t* Wm2bl = (half_t*)alloc((size_t)64 * 128 * 2);
    half_t* slab  = (half_t*)alloc((size_t)N * 896 * 2);
    (void)ws_size;

    const int TPB = 256;
    const int nb = (N + 1023) / 1024;
    zero_i32<<<(N + TPB - 1) / TPB, TPB, 0, stream>>>(deg, N);
    zero_i32<<<(N + TPB - 1) / TPB, TPB, 0, stream>>>(cur, N);
    count_deg<<<(E + TPB - 1) / TPB, TPB, 0, stream>>>(col, deg, E);
    compute_dis_s<<<(N + TPB - 1) / TPB, TPB, 0, stream>>>(deg, dis, sA, rsA, N);
    scan_blk<<<nb, 1024, 0, stream>>>(deg, off, bsum, N);
    scan_top<<<1, 64, 0, stream>>>(bsum, nb);
    scan_add<<<nb, 1024, 0, stream>>>(off, bsum, N);
    fill_edges<<<(E + TPB - 1) / TPB, TPB, 0, stream>>>(row, col, off, cur, esrc, E);
    conv_all<<<(253952 + TPB - 1) / TPB, TPB, 0, stream>>>(
        lins1, lins2, m1w1, m1w2, m2w1, m2w2, Wc1h, Wc1l, Wc2h, Wc2l, Wm1ah, Wm1al, Wm1bh,
        Wm1bl, Wm2ah, Wm2al, Wm2bh, Wm2bl);
    conv_xg<<<(N * 128 + TPB - 1) / TPB, TPB, 0, stream>>>(x, slab, g0, dis, sA, N * 128);

    unsigned* slabU = (unsigned*)slab;
    unsigned* g0U = (unsigned*)g0;
    const int HG = (N + 63) / 64;
    auto launch_prop = [&](const unsigned* gi, int idl, unsigned* go, int odl) {
        prop<<<2048, 256, 0, stream>>>(gi, idl, go, odl, dis, off, esrc, N);
    };

    // ---- Layer 1: 6 hops into slab cols 1..6 ----
    launch_prop(g0U, 64, slabU + 64, 448);
    for (int k = 2; k <= 6; ++k)
        launch_prop(slabU + (size_t)(k - 1) * 64, 448, slabU + (size_t)k * 64, 448);
    // concat GEMM K=896 -> ACC
    gemm<128, 0><<<dim3(HG, 1), 256, 0, stream>>>(
        N, 14, slab, 896, Wc1h, Wc1l, 896, ACC, 128, rsA, 1, bias1, nullptr, nullptr, nullptr, 0,
        nullptr, nullptr, 0, nullptr);
    // MLP1a: Z = relu(bn(ACC@W+b))  [N,256]
    gemm<128, 0><<<dim3(HG, 2), 256, 0, stream>>>(
        N, 2, ACC, 128, Wm1ah, Wm1al, 128, Z, 256, nullptr, 2, m1b1, bn1g, bn1b, nullptr, 0,
        nullptr, nullptr, 0, nullptr);
    // MLP1b: h1 = relu(Z@W+b); slab col0 = s*h1, g0 = dis*h1
    gemm<128, 0><<<dim3(HG, 1), 256, 0, stream>>>(
        N, 4, Z, 256, Wm1bh, Wm1bl, 256, nullptr, 0, nullptr, 3, m1b2, nullptr, nullptr, slab,
        896, sA, g0, 128, dis);

    // ---- Layer 2: 6 hops ----
    launch_prop(g0U, 64, slabU + 64, 448);
    for (int k = 2; k <= 6; ++k)
        launch_prop(slabU + (size_t)(k - 1) * 64, 448, slabU + (size_t)k * 64, 448);
    // concat GEMM K=896, Ntot=64 -> ACC2
    gemm<64, 0><<<dim3(HG, 1), 256, 0, stream>>>(
        N, 14, slab, 896, Wc2h, Wc2l, 896, ACC2, 64, rsA, 1, bias2, nullptr, nullptr, nullptr, 0,
        nullptr, nullptr, 0, nullptr);
    // MLP2a: Z2 = relu(bn(ACC2@W+b)) [N,128] (reuse Z)
    gemm<128, 0><<<dim3(HG, 1), 256, 0, stream>>>(
        N, 1, ACC2, 64, Wm2ah, Wm2al, 64, Z, 128, nullptr, 2, m2b1, bn2g, bn2b, nullptr, 0,
        nullptr, nullptr, 0, nullptr);
    // MLP2b: out = Z2@W + b (fp32)
    gemm<64, 1><<<dim3(HG, 1), 256, 0, stream>>>(
        N, 2, Z, 128, Wm2bh, Wm2bl, 128, out, 64, nullptr, 1, m2b2, nullptr, nullptr, nullptr, 0,
        nullptr, nullptr, 0, nullptr);
}

// Round 9
// 712.979 us; speedup vs baseline: 1.3548x; 1.0556x over previous
//
#include <hip/hip_runtime.h>
#include <hip/hip_bf16.h>

// TAGConv x2 GNN on MI355X. v9:
//  - layer 1: v8 path (6 props @128ch into slab, concat-K GEMM, rs-recovery).
//  - layer 2: weight-commuted Horner. P = h1 @ [W2_0|...|W2_6] (one GEMM,
//    concat-N, [N,448]); then u <- p_j + EPS*indeg*t_j + M u, 6 props @64ch
//    (halved gather bytes + footprint). t_j = 1^T sum_{k>j} W2_k; bias2 in
//    the final step. Exact: M commutes with right-multiplication; eps terms
//    are rank-1 and reproduce under Horner with the constant d=indeg vector.
//  - GEMM: global_load_lds staging, XOR-swizzle, dbuf LDS (v8).

#define EPS_MSG 1e-7f
#define BNSCALE 0.9999950000374997f  // 1/sqrt(1+1e-5)
#define LO_INV 0.0009765625f         // 2^-10

typedef _Float16 half_t;
typedef _Float16 f16x8 __attribute__((ext_vector_type(8)));
typedef float f32x4 __attribute__((ext_vector_type(4)));

__device__ __forceinline__ void gld16(const char* g, char* l) {
    __builtin_amdgcn_global_load_lds(
        (const __attribute__((address_space(1))) void*)g,
        (__attribute__((address_space(3))) void*)l, 16, 0, 0);
}

__device__ __forceinline__ float hlo(unsigned p) {
    unsigned short u = (unsigned short)(p & 0xffffu);
    half_t h;
    __builtin_memcpy(&h, &u, 2);
    return (float)h;
}
__device__ __forceinline__ float hhi(unsigned p) {
    unsigned short u = (unsigned short)(p >> 16);
    half_t h;
    __builtin_memcpy(&h, &u, 2);
    return (float)h;
}
__device__ __forceinline__ unsigned fpack2(float x, float y) {
    half_t a = (half_t)x, b = (half_t)y;
    unsigned short ua, ub;
    __builtin_memcpy(&ua, &a, 2);
    __builtin_memcpy(&ub, &b, 2);
    return (unsigned)ua | ((unsigned)ub << 16);
}

// ---------------- CSR build ----------------

__global__ void zero_i32(int* __restrict__ p, int n) {
    int i = blockIdx.x * blockDim.x + threadIdx.x;
    if (i < n) p[i] = 0;
}

__global__ void count_deg(const int* __restrict__ col, int* __restrict__ deg, int E) {
    int e = blockIdx.x * blockDim.x + threadIdx.x;
    if (e < E) atomicAdd(&deg[col[e]], 1);
}

__global__ void compute_dis_s(const int* __restrict__ deg, float* __restrict__ dis,
                              float* __restrict__ s, float* __restrict__ rs, int N) {
    int v = blockIdx.x * blockDim.x + threadIdx.x;
    if (v >= N) return;
    int d = deg[v];
    float di = (d > 0) ? rsqrtf((float)d) : 0.f;
    dis[v] = di;
    s[v] = (d > 0) ? di : 1.f;
    rs[v] = (d > 0) ? sqrtf((float)d) : 1.f;
}

__global__ void scan_blk(const int* __restrict__ deg, int* __restrict__ off,
                         int* __restrict__ bsum, int N) {
    __shared__ int sm[1024];
    int i = blockIdx.x * 1024 + threadIdx.x;
    sm[threadIdx.x] = (i < N) ? deg[i] : 0;
    __syncthreads();
    for (int ofs = 1; ofs < 1024; ofs <<= 1) {
        int t = (threadIdx.x >= (unsigned)ofs) ? sm[threadIdx.x - ofs] : 0;
        __syncthreads();
        sm[threadIdx.x] += t;
        __syncthreads();
    }
    if (i < N) off[i + 1] = sm[threadIdx.x];
    if (threadIdx.x == 0) bsum[blockIdx.x] = sm[1023];
}

__global__ void scan_top(int* __restrict__ bsum, int nb) {
    if (threadIdx.x == 0 && blockIdx.x == 0) {
        int a = 0;
        for (int b = 0; b < nb; ++b) {
            int t = bsum[b];
            bsum[b] = a;
            a += t;
        }
    }
}

__global__ void scan_add(int* __restrict__ off, const int* __restrict__ bsum, int N) {
    int i = blockIdx.x * 1024 + threadIdx.x;
    if (i < N) off[i + 1] += bsum[blockIdx.x];
    if (i == 0) off[0] = 0;
}

__global__ void fill_edges(const int* __restrict__ row, const int* __restrict__ col,
                           const int* __restrict__ off, int* __restrict__ cur,
                           unsigned short* __restrict__ esrc, int E) {
    int e = blockIdx.x * blockDim.x + threadIdx.x;
    if (e >= E) return;
    int c = col[e];
    int pos = off[c] + atomicAdd(&cur[c], 1);
    esrc[pos] = (unsigned short)row[e];
}

// ---------------- conversions ----------------

__global__ void conv_xg(const float* __restrict__ x, half_t* __restrict__ slab,
                        half_t* __restrict__ g0, const float* __restrict__ dis,
                        const float* __restrict__ s, int total) {
    int i = blockIdx.x * blockDim.x + threadIdx.x;
    if (i >= total) return;
    int v = i >> 7, c = i & 127;
    float xv = x[i];
    slab[(size_t)v * 896 + c] = (half_t)(s[v] * xv);
    g0[i] = (half_t)(dis[v] * fmaxf(xv, 0.f));
}

__device__ __forceinline__ void wcv(const float* __restrict__ in, half_t* __restrict__ oh,
                                    half_t* __restrict__ ol, int nm, int K, int Nn, int i) {
    int KT = nm * K;
    int n = i / KT;
    int rem = i - n * KT;
    int km = rem / K, k = rem - km * K;
    float w = in[(size_t)km * K * Nn + (size_t)k * Nn + n];
    half_t h = (half_t)w;
    oh[i] = h;
    ol[i] = (half_t)((w - (float)h) * 1024.f);
}

__global__ void conv_all(const float* l1, const float* l2, const float* a1, const float* b1,
                         const float* a2, const float* b2, half_t* W1h, half_t* W1l,
                         half_t* W2h, half_t* W2l, half_t* M1ah, half_t* M1al, half_t* M1bh,
                         half_t* M1bl, half_t* M2ah, half_t* M2al, half_t* M2bh,
                         half_t* M2bl) {
    int i = blockIdx.x * blockDim.x + threadIdx.x;
    if (i < 114688) {
        wcv(l1, W1h, W1l, 7, 128, 128, i);  // concat-K layout for layer-1
    } else if (i < 172032) {
        // W2: concat-N layout. B^T[np][k], np = km*64+n, value = l2[km][k][n]
        int j = i - 114688;
        int np = j >> 7, k = j & 127;
        int km = np >> 6, n = np & 63;
        float w = l2[(size_t)km * 128 * 64 + (size_t)k * 64 + n];
        half_t h = (half_t)w;
        W2h[j] = h;
        W2l[j] = (half_t)((w - (float)h) * 1024.f);
    } else if (i < 204800) {
        wcv(a1, M1ah, M1al, 1, 128, 256, i - 172032);
    } else if (i < 237568) {
        wcv(b1, M1bh, M1bl, 1, 256, 128, i - 204800);
    } else if (i < 245760) {
        wcv(a2, M2ah, M2al, 1, 64, 128, i - 237568);
    } else if (i < 253952) {
        wcv(b2, M2bh, M2bl, 1, 128, 64, i - 245760);
    }
}

// T[j][c] = sum_{k=j+1..6} sum_kk l2[k][kk][c], j=0..5
__global__ void conv_trows(const float* __restrict__ l2, float* __restrict__ T) {
    int j = threadIdx.x >> 6;
    int c = threadIdx.x & 63;
    if (j >= 6) return;
    float a = 0.f;
    for (int k = j + 1; k <= 6; ++k)
        for (int kk = 0; kk < 128; ++kk) a += l2[(size_t)k * 128 * 64 + kk * 64 + c];
    T[j * 64 + c] = a;
}

// ---------------- propagation, 128ch (layer 1) ----------------

__global__ void __launch_bounds__(256) prop(const unsigned* __restrict__ gin, int idl,
                                            unsigned* __restrict__ gout, int odl,
                                            const float* __restrict__ dis,
                                            const int* __restrict__ off,
                                            const unsigned short* __restrict__ esrc, int N) {
    const int lane = threadIdx.x & 63;
    const int w = threadIdx.x >> 6;
    const int stride = gridDim.x * 4;
    for (int v = blockIdx.x * 4 + w; v < N; v += stride) {
        int s = off[v], e = off[v + 1];
        float2 A0 = {0.f, 0.f}, A1 = {0.f, 0.f}, A2 = {0.f, 0.f}, A3 = {0.f, 0.f};
        float2 A4 = {0.f, 0.f}, A5 = {0.f, 0.f}, A6 = {0.f, 0.f}, A7 = {0.f, 0.f};
        for (int i = s; i < e; i += 8) {
            unsigned p[8];
            int ok[8];
#pragma unroll
            for (int j = 0; j < 8; ++j) {
                int ij = i + j;
                ok[j] = ij < e;
                int idx = ok[j] ? ij : e - 1;
                p[j] = gin[esrc[idx] * idl + lane];
            }
            A0.x += ok[0] ? hlo(p[0]) : 0.f; A0.y += ok[0] ? hhi(p[0]) : 0.f;
            A1.x += ok[1] ? hlo(p[1]) : 0.f; A1.y += ok[1] ? hhi(p[1]) : 0.f;
            A2.x += ok[2] ? hlo(p[2]) : 0.f; A2.y += ok[2] ? hhi(p[2]) : 0.f;
            A3.x += ok[3] ? hlo(p[3]) : 0.f; A3.y += ok[3] ? hhi(p[3]) : 0.f;
            A4.x += ok[4] ? hlo(p[4]) : 0.f; A4.y += ok[4] ? hhi(p[4]) : 0.f;
            A5.x += ok[5] ? hlo(p[5]) : 0.f; A5.y += ok[5] ? hhi(p[5]) : 0.f;
            A6.x += ok[6] ? hlo(p[6]) : 0.f; A6.y += ok[6] ? hhi(p[6]) : 0.f;
            A7.x += ok[7] ? hlo(p[7]) : 0.f; A7.y += ok[7] ? hhi(p[7]) : 0.f;
        }
        float ax = ((A0.x + A1.x) + (A2.x + A3.x)) + ((A4.x + A5.x) + (A6.x + A7.x));
        float ay = ((A0.y + A1.y) + (A2.y + A3.y)) + ((A4.y + A5.y) + (A6.y + A7.y));
        float dv = dis[v];
        float ce = (float)(e - s) * EPS_MSG;
        float hx = fmaf(dv, ax, ce);
        float hy = fmaf(dv, ay, ce);
        gout[v * odl + lane] = fpack2(dv * hx, dv * hy);
    }
}

// ---------------- propagation, 64ch Horner step (layer 2) ----------------
// u_out = p_j + EPS*indeg*t_j + M u_in ; store dis*u_out (or +bias2 unscaled if FINAL)

template <int FINAL>
__global__ void __launch_bounds__(256) prop64(
    const half_t* __restrict__ uin, int ldu, const half_t* __restrict__ pj, int ldp,
    half_t* __restrict__ uout, int ldo, const float* __restrict__ dis,
    const int* __restrict__ off, const unsigned short* __restrict__ esrc,
    const float* __restrict__ tj, const float* __restrict__ bias2, int N) {
    const int c = threadIdx.x & 63;
    const int w = threadIdx.x >> 6;
    const int stride = gridDim.x * 4;
    for (int v = blockIdx.x * 4 + w; v < N; v += stride) {
        int s = off[v], e = off[v + 1];
        float a0 = 0.f, a1 = 0.f, a2 = 0.f, a3 = 0.f;
        float a4 = 0.f, a5 = 0.f, a6 = 0.f, a7 = 0.f;
        for (int i = s; i < e; i += 8) {
            float q[8];
            int ok[8];
#pragma unroll
            for (int j = 0; j < 8; ++j) {
                int ij = i + j;
                ok[j] = ij < e;
                int idx = ok[j] ? ij : e - 1;
                q[j] = (float)uin[(size_t)esrc[idx] * ldu + c];
            }
            a0 += ok[0] ? q[0] : 0.f;
            a1 += ok[1] ? q[1] : 0.f;
            a2 += ok[2] ? q[2] : 0.f;
            a3 += ok[3] ? q[3] : 0.f;
            a4 += ok[4] ? q[4] : 0.f;
            a5 += ok[5] ? q[5] : 0.f;
            a6 += ok[6] ? q[6] : 0.f;
            a7 += ok[7] ? q[7] : 0.f;
        }
        float acc = ((a0 + a1) + (a2 + a3)) + ((a4 + a5) + (a6 + a7));
        float dv = dis[v];
        float base = (float)pj[(size_t)v * ldp + c] + (float)(e - s) * EPS_MSG * tj[c];
        float u = fmaf(dv, acc, base);
        if (FINAL)
            uout[(size_t)v * ldo + c] = (half_t)(u + bias2[c]);
        else
            uout[(size_t)v * ldo + c] = (half_t)(dv * u);
    }
}

// ---------------- f16 MFMA GEMM (global_load_lds, swizzled, dbuf LDS) -------
// C[M,*](ldc) = epi( rs .* (A[M,K] @ (Bh + Bl/1024)^T) ), B rows offset by noff.
// epi: 0=none 1=+bias 2=relu(bn(v+bias)) 3=relu(v+bias)

template <int BN, int OUTF32>
__global__ __launch_bounds__(256) void gemm(
    int M, int kiters, const half_t* __restrict__ A, int lda,
    const half_t* __restrict__ Bhp, const half_t* __restrict__ Blp, int ldb, int noff,
    void* __restrict__ Cp, int ldc, const float* __restrict__ rs, int epi,
    const float* __restrict__ bias, const float* __restrict__ bng,
    const float* __restrict__ bnb) {
    constexpr int BM = 64, BK = 64;
    constexpr int WC = (BN == 128) ? 2 : 1;
    constexpr int WROWS = BM / (4 / WC);  // 32 or 16
    constexpr int MF = WROWS / 16;
    constexpr int NF = 4;
    constexpr int ABY = BM * BK * 2;
    constexpr int BBY = BN * BK * 2;
    constexpr int BUFBY = ABY + 2 * BBY;
    constexpr int ACW = (ABY / 1024) / 4;
    constexpr int BCW = (BBY / 1024) / 4;

    __shared__ char lds[2][BUFBY];

    const int tid = threadIdx.x;
    const int lane = tid & 63;
    const int w = tid >> 6;
    const int wr = w / WC, wc = w % WC;
    const int m0 = blockIdx.x * BM;
    const int n0 = blockIdx.y * BN + noff;
    const int l15 = lane & 15, lq = lane >> 4;
    const int lr8 = lane >> 3, lc8 = lane & 7;

    const char* gA = (const char*)A;
    const char* gBh = (const char*)Bhp;
    const char* gBl = (const char*)Blp;
    const size_t ldaB = (size_t)lda * 2, ldbB = (size_t)ldb * 2;

    auto stage = [&](int kt, int buf) {
        const int k0b = kt * BK * 2;
        char* base = lds[0] + buf * BUFBY;
#pragma unroll
        for (int i = 0; i < ACW; ++i) {
            int c = w * ACW + i;
            int r = c * 8 + lr8;
            int gv = m0 + r;
            if (gv >= M) gv = M - 1;
            int sc = (lc8 ^ (r & 7)) << 4;
            gld16(gA + (size_t)gv * ldaB + k0b + sc, base + c * 1024);
        }
#pragma unroll
        for (int i = 0; i < BCW; ++i) {
            int c = w * BCW + i;
            int r = c * 8 + lr8;
            int sc = (lc8 ^ (r & 7)) << 4;
            size_t goff = (size_t)(n0 + r) * ldbB + k0b + sc;
            gld16(gBh + goff, base + ABY + c * 1024);
            gld16(gBl + goff, base + ABY + BBY + c * 1024);
        }
    };

    f32x4 acch[MF][NF], accl[MF][NF];
#pragma unroll
    for (int fm = 0; fm < MF; ++fm)
#pragma unroll
        for (int fn = 0; fn < NF; ++fn) {
            acch[fm][fn] = (f32x4){0.f, 0.f, 0.f, 0.f};
            accl[fm][fn] = (f32x4){0.f, 0.f, 0.f, 0.f};
        }

    auto compute = [&](int buf) {
        const char* Ab = lds[0] + buf * BUFBY;
        const char* Bhb = Ab + ABY;
        const char* Blb = Ab + ABY + BBY;
#pragma unroll
        for (int ks = 0; ks < 2; ++ks) {
            const int cc = ks * 4 + lq;
            f16x8 af[MF];
#pragma unroll
            for (int fm = 0; fm < MF; ++fm) {
                int r = wr * WROWS + fm * 16 + l15;
                af[fm] = *(const f16x8*)(Ab + r * 128 + ((cc ^ (r & 7)) << 4));
            }
#pragma unroll
            for (int fn = 0; fn < NF; ++fn) {
                int r = wc * 64 + fn * 16 + l15;
                int o = r * 128 + ((cc ^ (r & 7)) << 4);
                f16x8 bhv = *(const f16x8*)(Bhb + o);
                f16x8 blv = *(const f16x8*)(Blb + o);
#pragma unroll
                for (int fm = 0; fm < MF; ++fm) {
                    acch[fm][fn] =
                        __builtin_amdgcn_mfma_f32_16x16x32_f16(af[fm], bhv, acch[fm][fn], 0, 0, 0);
                    accl[fm][fn] =
                        __builtin_amdgcn_mfma_f32_16x16x32_f16(af[fm], blv, accl[fm][fn], 0, 0, 0);
                }
            }
        }
    };

    stage(0, 0);
    int buf = 0;
    for (int kt = 0; kt < kiters; ++kt) {
        __syncthreads();
        if (kt + 1 < kiters) stage(kt + 1, buf ^ 1);
        compute(buf);
        buf ^= 1;
    }

#pragma unroll
    for (int fm = 0; fm < MF; ++fm)
#pragma unroll
        for (int fn = 0; fn < NF; ++fn)
#pragma unroll
            for (int i = 0; i < 4; ++i) {
                int gr = m0 + wr * WROWS + fm * 16 + (lane >> 4) * 4 + i;
                if (gr >= M) continue;
                int gc = n0 + wc * 64 + fn * 16 + (lane & 15);
                float v = acch[fm][fn][i] + accl[fm][fn][i] * LO_INV;
                if (rs) v *= rs[gr];
                if (epi == 1) {
                    v += bias[gc];
                } else if (epi == 2) {
                    v = bng[gc] * ((v + bias[gc]) * BNSCALE) + bnb[gc];
                    v = fmaxf(v, 0.f);
                } else if (epi == 3) {
                    v = fmaxf(v + bias[gc], 0.f);
                }
                if (OUTF32)
                    ((float*)Cp)[(size_t)gr * ldc + gc] = v;
                else
                    ((half_t*)Cp)[(size_t)gr * ldc + gc] = (half_t)v;
            }
}

extern "C" void kernel_launch(void* const* d_in, const int* in_sizes, int n_in,
                              void* d_out, int out_size, void* d_ws, size_t ws_size,
                              hipStream_t stream) {
    const float* x     = (const float*)d_in[0];
    const int*   ei    = (const int*)d_in[1];
    const float* lins1 = (const float*)d_in[2];
    const float* bias1 = (const float*)d_in[3];
    const float* m1w1  = (const float*)d_in[4];
    const float* m1b1  = (const float*)d_in[5];
    const float* bn1g  = (const float*)d_in[6];
    const float* bn1b  = (const float*)d_in[7];
    const float* m1w2  = (const float*)d_in[8];
    const float* m1b2  = (const float*)d_in[9];
    const float* lins2 = (const float*)d_in[10];
    const float* bias2 = (const float*)d_in[11];
    const float* m2w1  = (const float*)d_in[12];
    const float* m2b1  = (const float*)d_in[13];
    const float* bn2g  = (const float*)d_in[14];
    const float* bn2b  = (const float*)d_in[15];
    const float* m2w2  = (const float*)d_in[16];
    const float* m2b2  = (const float*)d_in[17];
    float* out = (float*)d_out;

    const int N = in_sizes[0] / 128;
    const int E = in_sizes[1] / 2;
    const int* row = ei;
    const int* col = ei + E;

    char* ws = (char*)d_ws;
    size_t o = 0;
    auto alloc = [&](size_t bytes) {
        void* p = ws + o;
        o += (bytes + 255) & ~(size_t)255;
        return p;
    };
    int*            deg  = (int*)alloc((size_t)N * 4);
    int*            cur  = (int*)alloc((size_t)N * 4);
    float*          dis  = (float*)alloc((size_t)N * 4);
    float*          sA   = (float*)alloc((size_t)N * 4);
    float*          rsA  = (float*)alloc((size_t)N * 4);
    int*            off  = (int*)alloc((size_t)(N + 1) * 4);
    int*            bsum = (int*)alloc(1024 * 4);
    float*          Trow = (float*)alloc(6 * 64 * 4);
    unsigned short* esrc = (unsigned short*)alloc((size_t)E * 2);
    half_t* g0    = (half_t*)alloc((size_t)N * 128 * 2);
    half_t* ACC   = (half_t*)alloc((size_t)N * 128 * 2);
    half_t* Z     = (half_t*)alloc((size_t)N * 256 * 2);
    half_t* H1    = (half_t*)alloc((size_t)N * 128 * 2);
    half_t* ACC2  = (half_t*)alloc((size_t)N * 64 * 2);
    half_t* Wc1h  = (half_t*)alloc((size_t)128 * 896 * 2);
    half_t* Wc1l  = (half_t*)alloc((size_t)128 * 896 * 2);
    half_t* Wc2h  = (half_t*)alloc((size_t)448 * 128 * 2);
    half_t* Wc2l  = (half_t*)alloc((size_t)448 * 128 * 2);
    half_t* Wm1ah = (half_t*)alloc((size_t)256 * 128 * 2);
    half_t* Wm1al = (half_t*)alloc((size_t)256 * 128 * 2);
    half_t* Wm1bh = (half_t*)alloc((size_t)128 * 256 * 2);
    half_t* Wm1bl = (half_t*)alloc((size_t)128 * 256 * 2);
    half_t* Wm2ah = (half_t*)alloc((size_t)128 * 64 * 2);
    half_t* Wm2al = (half_t*)alloc((size_t)128 * 64 * 2);
    half_t* Wm2bh = (half_t*)alloc((size_t)64 * 128 * 2);
    half_t* Wm2bl = (half_t*)alloc((size_t)64 * 128 * 2);
    half_t* slab  = (half_t*)alloc((size_t)N * 896 * 2);
    (void)ws_size;

    const int TPB = 256;
    const int nb = (N + 1023) / 1024;
    zero_i32<<<(N + TPB - 1) / TPB, TPB, 0, stream>>>(deg, N);
    zero_i32<<<(N + TPB - 1) / TPB, TPB, 0, stream>>>(cur, N);
    count_deg<<<(E + TPB - 1) / TPB, TPB, 0, stream>>>(col, deg, E);
    compute_dis_s<<<(N + TPB - 1) / TPB, TPB, 0, stream>>>(deg, dis, sA, rsA, N);
    scan_blk<<<nb, 1024, 0, stream>>>(deg, off, bsum, N);
    scan_top<<<1, 64, 0, stream>>>(bsum, nb);
    scan_add<<<nb, 1024, 0, stream>>>(off, bsum, N);
    fill_edges<<<(E + TPB - 1) / TPB, TPB, 0, stream>>>(row, col, off, cur, esrc, E);
    conv_all<<<(253952 + TPB - 1) / TPB, TPB, 0, stream>>>(
        lins1, lins2, m1w1, m1w2, m2w1, m2w2, Wc1h, Wc1l, Wc2h, Wc2l, Wm1ah, Wm1al, Wm1bh,
        Wm1bl, Wm2ah, Wm2al, Wm2bh, Wm2bl);
    conv_trows<<<1, 384, 0, stream>>>(lins2, Trow);
    conv_xg<<<(N * 128 + TPB - 1) / TPB, TPB, 0, stream>>>(x, slab, g0, dis, sA, N * 128);

    unsigned* slabU = (unsigned*)slab;
    unsigned* g0U = (unsigned*)g0;
    const int HG = (N + 63) / 64;

    // ---- Layer 1: 6 hops @128ch into slab cols 1..6, concat-K GEMM ----
    prop<<<2048, 256, 0, stream>>>(g0U, 64, slabU + 64, 448, dis, off, esrc, N);
    for (int k = 2; k <= 6; ++k)
        prop<<<2048, 256, 0, stream>>>(slabU + (size_t)(k - 1) * 64, 448,
                                       slabU + (size_t)k * 64, 448, dis, off, esrc, N);
    gemm<128, 0><<<dim3(HG, 1), 256, 0, stream>>>(
        N, 14, slab, 896, Wc1h, Wc1l, 896, 0, ACC, 128, rsA, 1, bias1, nullptr, nullptr);
    // MLP1: Z = relu(bn(ACC@W+b)); h1 = relu(Z@W+b) -> H1
    gemm<128, 0><<<dim3(HG, 2), 256, 0, stream>>>(
        N, 2, ACC, 128, Wm1ah, Wm1al, 128, 0, Z, 256, nullptr, 2, m1b1, bn1g, bn1b);
    gemm<128, 0><<<dim3(HG, 1), 256, 0, stream>>>(
        N, 4, Z, 256, Wm1bh, Wm1bl, 256, 0, H1, 128, nullptr, 3, m1b2, nullptr, nullptr);

    // ---- Layer 2: P = H1 @ [W2_0..W2_6] (concat-N), slice 6 pre-scaled by dis ----
    gemm<64, 0><<<dim3(HG, 6), 256, 0, stream>>>(
        N, 2, H1, 128, Wc2h, Wc2l, 128, 0, slab, 448, nullptr, 0, nullptr, nullptr, nullptr);
    gemm<64, 0><<<dim3(HG, 1), 256, 0, stream>>>(
        N, 2, H1, 128, Wc2h, Wc2l, 128, 384, slab, 448, dis, 0, nullptr, nullptr, nullptr);

    // ---- Horner: u <- p_j + EPS*indeg*t_j + M u, 6 steps @64ch ----
    half_t* ub0 = g0;
    half_t* ub1 = g0 + (size_t)N * 64;
    prop64<0><<<2048, 256, 0, stream>>>(slab + 384, 448, slab + 320, 448, ub0, 64, dis, off,
                                        esrc, Trow + 5 * 64, nullptr, N);
    prop64<0><<<2048, 256, 0, stream>>>(ub0, 64, slab + 256, 448, ub1, 64, dis, off, esrc,
                                        Trow + 4 * 64, nullptr, N);
    prop64<0><<<2048, 256, 0, stream>>>(ub1, 64, slab + 192, 448, ub0, 64, dis, off, esrc,
                                        Trow + 3 * 64, nullptr, N);
    prop64<0><<<2048, 256, 0, stream>>>(ub0, 64, slab + 128, 448, ub1, 64, dis, off, esrc,
                                        Trow + 2 * 64, nullptr, N);
    prop64<0><<<2048, 256, 0, stream>>>(ub1, 64, slab + 64, 448, ub0, 64, dis, off, esrc,
                                        Trow + 1 * 64, nullptr, N);
    prop64<1><<<2048, 256, 0, stream>>>(ub0, 64, slab, 448, ACC2, 64, dis, off, esrc,
                                        Trow + 0 * 64, bias2, N);

    // ---- MLP2 ----
    gemm<128, 0><<<dim3(HG, 1), 256, 0, stream>>>(
        N, 1, ACC2, 64, Wm2ah, Wm2al, 64, 0, Z, 128, nullptr, 2, m2b1, bn2g, bn2b);
    gemm<64, 1><<<dim3(HG, 1), 256, 0, stream>>>(
        N, 2, Z, 128, Wm2bh, Wm2bl, 128, 0, out, 64, nullptr, 1, m2b2, nullptr, nullptr);
}